// Round 12
// baseline (262.786 us; speedup 1.0000x reference)
//
#include <hip/hip_runtime.h>
#include <hip/hip_bf16.h>
#include <stdint.h>

// x:(4,2048,1024)f32, Wq/Wk/Wv:(1024,1024)f32 -> out:(4,2048,1024)f32
// 5 dispatches: memset rs | cvt_all (x+W3->bf16) | merged QKV proj GEMM
//   (Q/K row-major, V transposed) | QK^T GEMM fused exp2+atomic rowsum |
//   E@V^T GEMM with inline 1/rowsum -> f32 out.
// GEMM core: measured round-2/round-10 structure, UNCHANGED — 128x128 tile,
// BK=32, 4 waves, global_load_lds w16, chunk-XOR swizzle, double-buffered LDS.

typedef short bf16x8 __attribute__((ext_vector_type(8)));
typedef float f32x4  __attribute__((ext_vector_type(4)));

__device__ __forceinline__ unsigned short f2bf(float f) {
  unsigned u = __float_as_uint(f);
  u += 0x7fff + ((u >> 16) & 1);   // RNE; inputs are finite
  return (unsigned short)(u >> 16);
}

// One kernel converts x (2,097,152 float4s) then stacked Wq|Wk|Wv (786,432 float4s).
__global__ __launch_bounds__(256) void cvt_all(
    const float* __restrict__ x, const float* __restrict__ Wq,
    const float* __restrict__ Wk, const float* __restrict__ Wv,
    unsigned short* __restrict__ xb, unsigned short* __restrict__ W3) {
  int i = blockIdx.x * 256 + threadIdx.x;  // float4 index
  const int XF4 = 2097152;
  if (i < XF4) {
    float4 v = *(const float4*)(x + (size_t)i * 4);
    ushort4 o;
    o.x = f2bf(v.x); o.y = f2bf(v.y); o.z = f2bf(v.z); o.w = f2bf(v.w);
    *(ushort4*)(xb + (size_t)i * 4) = o;
  } else {
    int j = i - XF4;            // 0..786431; 256 float4s per 1024-elem row
    int row = j >> 8;           // stacked row 0..3071 (block-uniform)
    const float* s = (row < 1024) ? Wq : (row < 2048) ? Wk : Wv;
    int off = (row & 1023) * 1024 + (j & 255) * 4;
    float4 v = *(const float4*)(s + off);
    ushort4 o;
    o.x = f2bf(v.x); o.y = f2bf(v.y); o.z = f2bf(v.z); o.w = f2bf(v.w);
    *(ushort4*)(W3 + (size_t)j * 4) = o;
  }
}

__device__ __forceinline__ void gload_lds16(const void* g, void* l) {
  __builtin_amdgcn_global_load_lds(
      (const __attribute__((address_space(1))) unsigned int*)g,
      (__attribute__((address_space(3))) unsigned int*)l, 16, 0, 0);
}

// NT GEMM: C[m][n] = sum_k A[m][k]*B[n][k]; A,B bf16 row-major K-contig.
// Tile 128x128, BK=32, 4 waves (2x2 of 64x64), 16x16x32 MFMA.
// LDS chunk swizzle: 16B chunk kg stored at kg ^ ((row>>1)&3) (pre-swizzled src).
// STORE 0: merged QKV. Cv=QK ([2][8192][1024] bf16), aux=Vt ([4][1024][2048] bf16).
//          c<2048 -> Q/K row-major; c>=2048 -> V transposed (block-uniform).
// STORE 3: E = bf16(exp2(acc*log2e/32)) into Cv (+bz*4M), atomic rowsum into aux.
// STORE 4: PV: f32 out (+bz*strideC) scaled inline by 1/aux[r] (raw rowsums).
template<int STORE>
__global__ __launch_bounds__(256, 2) void gemm_nt(
    const unsigned short* __restrict__ A, const unsigned short* __restrict__ B,
    void* __restrict__ Cv, float* __restrict__ aux, int lda, int ldb, int ldc, int K,
    long strideA, long strideB, long strideC) {
  __shared__ __align__(16) unsigned short lds[2][2][128 * 32];
  const int tid  = threadIdx.x;
  const int lane = tid & 63;
  const int wid  = tid >> 6;
  const int bz   = blockIdx.z;
  const unsigned short* Ab = A + (size_t)bz * strideA;
  const unsigned short* Bb = B + (size_t)bz * strideB;
  const int row0 = blockIdx.x * 128;
  const int col0 = blockIdx.y * 128;

  f32x4 acc[4][4];
#pragma unroll
  for (int m = 0; m < 4; ++m)
#pragma unroll
    for (int n = 0; n < 4; ++n) acc[m][n] = f32x4{0.f, 0.f, 0.f, 0.f};

  const int KT = K >> 5;

  auto stage = [&](int buf, int kt) {
    const int k0 = kt << 5;
#pragma unroll
    for (int it = 0; it < 2; ++it) {
      int j   = it * 256 + tid;       // 512 chunks of 16B per operand tile
      int r   = j >> 2;               // tile row 0..127
      int kg  = j & 3;                // 16B chunk within row
      int kgS = kg ^ ((r >> 1) & 3);  // pre-swizzled global source (LDS stays linear)
      gload_lds16(Ab + (size_t)(row0 + r) * lda + k0 + kgS * 8, &lds[buf][0][j * 8]);
      gload_lds16(Bb + (size_t)(col0 + r) * ldb + k0 + kgS * 8, &lds[buf][1][j * 8]);
    }
  };

  stage(0, 0);
  int buf = 0;
  for (int kt = 0; kt < KT; ++kt) {
    __syncthreads();  // drains vmcnt for staged buf; also guards re-stage of other buf
    if (kt + 1 < KT) stage(buf ^ 1, kt + 1);
    const unsigned short* As = &lds[buf][0][0];
    const unsigned short* Bs = &lds[buf][1][0];
    const int kg = lane >> 4;
    const int lr = lane & 15;
    bf16x8 af[4], bfr[4];
#pragma unroll
    for (int m = 0; m < 4; ++m) {
      int r = ((wid >> 1) * 64) + m * 16 + lr;
      af[m] = *(const bf16x8*)(As + r * 32 + ((kg ^ ((r >> 1) & 3)) * 8));
    }
#pragma unroll
    for (int n = 0; n < 4; ++n) {
      int c = ((wid & 1) * 64) + n * 16 + lr;
      bfr[n] = *(const bf16x8*)(Bs + c * 32 + ((kg ^ ((c >> 1) & 3)) * 8));
    }
#pragma unroll
    for (int m = 0; m < 4; ++m)
#pragma unroll
      for (int n = 0; n < 4; ++n)
        acc[m][n] = __builtin_amdgcn_mfma_f32_16x16x32_bf16(af[m], bfr[n], acc[m][n], 0, 0, 0);
    buf ^= 1;
  }

  // Epilogue. C/D layout: col = lane&15, row = (lane>>4)*4 + j  [m89-verified]
  const int wr0 = row0 + (wid >> 1) * 64;
  const int wc0 = col0 + (wid & 1) * 64;
  const int rj  = lane >> 4;
  const int cl  = lane & 15;
  if constexpr (STORE == 0) {
    // merged QKV: Q/K row-major into Cv, V transposed into aux (cast)
    unsigned short* QK = (unsigned short*)Cv;
    unsigned short* Vt = (unsigned short*)aux;
#pragma unroll
    for (int m = 0; m < 4; ++m) {
#pragma unroll
      for (int n = 0; n < 4; ++n) {
#pragma unroll
        for (int j = 0; j < 4; ++j) {
          int r = wr0 + m * 16 + rj * 4 + j;
          int c = wc0 + n * 16 + cl;
          unsigned short bv = f2bf(acc[m][n][j]);
          if (c < 2048) {   // Q (c<1024) / K — block-uniform branch
            QK[(size_t)(c >> 10) * 8388608 + (size_t)r * 1024 + (c & 1023)] = bv;
          } else {          // V transposed: [b][o][s]
            Vt[(size_t)(r >> 11) * 2097152 + (size_t)(c - 2048) * 2048 + (r & 2047)] = bv;
          }
        }
      }
    }
  } else if constexpr (STORE == 3) {
    // scores: E[r][c] = bf16(exp2(acc * log2e/32)); rowsum += sum of rounded E
    unsigned short* E = (unsigned short*)Cv + (size_t)bz * 4194304;
    float* rs = aux + bz * 2048;
    const float SC = 0.045084220027780106f;  // log2(e)/32
#pragma unroll
    for (int m = 0; m < 4; ++m) {
#pragma unroll
      for (int j = 0; j < 4; ++j) {
        int r = wr0 + m * 16 + rj * 4 + j;
        float part = 0.f;
#pragma unroll
        for (int n = 0; n < 4; ++n) {
          int c = wc0 + n * 16 + cl;
          unsigned short eb = f2bf(exp2f(acc[m][n][j] * SC));
          E[(size_t)r * 2048 + c] = eb;
          part += __uint_as_float((unsigned)eb << 16);  // sum the rounded values
        }
#pragma unroll
        for (int o = 1; o < 16; o <<= 1) part += __shfl_xor(part, o);
        if (cl == 0) atomicAdd(&rs[r], part);
      }
    }
  } else {
    // PV: scale by 1/rowsum computed inline (aux holds raw sums)
    float* C = (float*)Cv + (size_t)bz * strideC;
    const float* rs = aux + bz * 2048;
#pragma unroll
    for (int m = 0; m < 4; ++m) {
#pragma unroll
      for (int j = 0; j < 4; ++j) {
        int r = wr0 + m * 16 + rj * 4 + j;
        float inv = 1.0f / rs[r];
#pragma unroll
        for (int n = 0; n < 4; ++n) {
          int c = wc0 + n * 16 + cl;
          C[(size_t)r * ldc + c] = acc[m][n][j] * inv;
        }
      }
    }
  }
}

extern "C" void kernel_launch(void* const* d_in, const int* in_sizes, int n_in,
                              void* d_out, int out_size, void* d_ws, size_t ws_size,
                              hipStream_t stream) {
  const float* x  = (const float*)d_in[0];
  const float* Wq = (const float*)d_in[1];
  const float* Wk = (const float*)d_in[2];
  const float* Wv = (const float*)d_in[3];

  char* w = (char*)d_ws;
  // ws: xb 16M | W3 6M | Q,K 32M @22M | Vt 16M @54M | E 32M @70M | rs @102M
  unsigned short* xb = (unsigned short*)(w);
  unsigned short* W3 = (unsigned short*)(w + (16ull << 20));
  unsigned short* QK = (unsigned short*)(w + (22ull << 20));  // Q then K, 8M elems each
  unsigned short* Vt = (unsigned short*)(w + (54ull << 20));  // [b][o][s]
  unsigned short* E  = (unsigned short*)(w + (70ull << 20));  // [b][q][k] bf16 exp
  float*          rs = (float*)        (w + (102ull << 20));  // [b][q] raw rowsum

  hipMemsetAsync(rs, 0, 8192 * sizeof(float), stream);

  // fp32 -> bf16 (x and stacked W3) in one launch
  cvt_all<<<11264, 256, 0, stream>>>(x, Wq, Wk, Wv, xb, W3);

  // merged QKV: [8192x1024] @ [3072x1024]^T; Q/K row-major, V transposed
  gemm_nt<0><<<dim3(64, 24, 1), 256, 0, stream>>>(
      xb, W3, QK, (float*)Vt, 1024, 1024, 0, 1024, 0, 0, 0);
  // E = exp2((Q@K^T)*log2e/32) per batch, bf16; rowsums accumulated atomically
  gemm_nt<3><<<dim3(16, 16, 4), 256, 0, stream>>>(
      QK, QK + (8u << 20), E, rs, 1024, 1024, 2048, 1024,
      2ll << 20, 2ll << 20, 0);
  // out = (E @ V^T) * (1/rowsum), f32 straight to d_out
  gemm_nt<4><<<dim3(16, 8, 4), 256, 0, stream>>>(
      E, Vt, d_out, rs, 2048, 2048, 1024, 2048,
      4ll << 20, 2ll << 20, 2ll << 20);
}

// Round 13
// 251.341 us; speedup vs baseline: 1.0455x; 1.0455x over previous
//
#include <hip/hip_runtime.h>
#include <hip/hip_bf16.h>
#include <stdint.h>

// x:(4,2048,1024)f32, Wq/Wk/Wv:(1024,1024)f32 -> out:(4,2048,1024)f32
// 6 dispatches: memset rs | cvt_all (x + stacked W3 -> bf16) |
//   Q/K proj GEMM (z=2, row-major) | V proj GEMM (stored transposed) |
//   QK^T GEMM fused exp2 + atomic rowsum (bf16 E) |
//   E@V^T GEMM with inline 1/rowsum -> f32 out.
// GEMM core: measured round-2/10 structure, UNCHANGED — 128x128 tile, BK=32,
// 4 waves, global_load_lds w16, chunk-XOR swizzle, double-buffered LDS.
// Round-12 lesson: merged QKV proj = 556 TF vs split 662 TF -> keep split.
// Gap model: fixed ~33us + ~1.7us/dispatch -> dispatch count is exhausted.

typedef short bf16x8 __attribute__((ext_vector_type(8)));
typedef float f32x4  __attribute__((ext_vector_type(4)));

__device__ __forceinline__ unsigned short f2bf(float f) {
  unsigned u = __float_as_uint(f);
  u += 0x7fff + ((u >> 16) & 1);   // RNE; inputs are finite
  return (unsigned short)(u >> 16);
}

// One kernel converts x (2,097,152 float4s) then stacked Wq|Wk|Wv (786,432 float4s).
__global__ __launch_bounds__(256) void cvt_all(
    const float* __restrict__ x, const float* __restrict__ Wq,
    const float* __restrict__ Wk, const float* __restrict__ Wv,
    unsigned short* __restrict__ xb, unsigned short* __restrict__ W3) {
  int i = blockIdx.x * 256 + threadIdx.x;  // float4 index
  const int XF4 = 2097152;
  if (i < XF4) {
    float4 v = *(const float4*)(x + (size_t)i * 4);
    ushort4 o;
    o.x = f2bf(v.x); o.y = f2bf(v.y); o.z = f2bf(v.z); o.w = f2bf(v.w);
    *(ushort4*)(xb + (size_t)i * 4) = o;
  } else {
    int j = i - XF4;            // 0..786431; 256 float4s per 1024-elem row
    int row = j >> 8;           // stacked row 0..3071 (block-uniform)
    const float* s = (row < 1024) ? Wq : (row < 2048) ? Wk : Wv;
    int off = (row & 1023) * 1024 + (j & 255) * 4;
    float4 v = *(const float4*)(s + off);
    ushort4 o;
    o.x = f2bf(v.x); o.y = f2bf(v.y); o.z = f2bf(v.z); o.w = f2bf(v.w);
    *(ushort4*)(W3 + (size_t)j * 4) = o;
  }
}

__device__ __forceinline__ void gload_lds16(const void* g, void* l) {
  __builtin_amdgcn_global_load_lds(
      (const __attribute__((address_space(1))) unsigned int*)g,
      (__attribute__((address_space(3))) unsigned int*)l, 16, 0, 0);
}

// NT GEMM: C[m][n] = sum_k A[m][k]*B[n][k]; A,B bf16 row-major K-contig.
// Tile 128x128, BK=32, 4 waves (2x2 of 64x64), 16x16x32 MFMA.
// LDS chunk swizzle: 16B chunk kg stored at kg ^ ((row>>1)&3) (pre-swizzled src).
// STORE 0: bf16 row-major (+bz*strideC)                         [Q/K proj]
// STORE 2: bf16 transposed per batch: [(r>>11)*1024+c][r&2047]  [V proj]
// STORE 3: E = bf16(exp2(acc*SC)) into Cv (+bz*4M), atomic rowsum into aux
// STORE 4: f32 row-major (+bz*strideC), scaled inline by 1/aux[r]
template<int STORE>
__global__ __launch_bounds__(256, 2) void gemm_nt(
    const unsigned short* __restrict__ A, const unsigned short* __restrict__ B,
    void* __restrict__ Cv, float* __restrict__ aux, int lda, int ldb, int ldc, int K,
    long strideA, long strideB, long strideC) {
  __shared__ __align__(16) unsigned short lds[2][2][128 * 32];
  const int tid  = threadIdx.x;
  const int lane = tid & 63;
  const int wid  = tid >> 6;
  const int bz   = blockIdx.z;
  const unsigned short* Ab = A + (size_t)bz * strideA;
  const unsigned short* Bb = B + (size_t)bz * strideB;
  const int row0 = blockIdx.x * 128;
  const int col0 = blockIdx.y * 128;

  f32x4 acc[4][4];
#pragma unroll
  for (int m = 0; m < 4; ++m)
#pragma unroll
    for (int n = 0; n < 4; ++n) acc[m][n] = f32x4{0.f, 0.f, 0.f, 0.f};

  const int KT = K >> 5;

  auto stage = [&](int buf, int kt) {
    const int k0 = kt << 5;
#pragma unroll
    for (int it = 0; it < 2; ++it) {
      int j   = it * 256 + tid;       // 512 chunks of 16B per operand tile
      int r   = j >> 2;               // tile row 0..127
      int kg  = j & 3;                // 16B chunk within row
      int kgS = kg ^ ((r >> 1) & 3);  // pre-swizzled global source (LDS stays linear)
      gload_lds16(Ab + (size_t)(row0 + r) * lda + k0 + kgS * 8, &lds[buf][0][j * 8]);
      gload_lds16(Bb + (size_t)(col0 + r) * ldb + k0 + kgS * 8, &lds[buf][1][j * 8]);
    }
  };

  stage(0, 0);
  int buf = 0;
  for (int kt = 0; kt < KT; ++kt) {
    __syncthreads();  // drains vmcnt for staged buf; also guards re-stage of other buf
    if (kt + 1 < KT) stage(buf ^ 1, kt + 1);
    const unsigned short* As = &lds[buf][0][0];
    const unsigned short* Bs = &lds[buf][1][0];
    const int kg = lane >> 4;
    const int lr = lane & 15;
    bf16x8 af[4], bfr[4];
#pragma unroll
    for (int m = 0; m < 4; ++m) {
      int r = ((wid >> 1) * 64) + m * 16 + lr;
      af[m] = *(const bf16x8*)(As + r * 32 + ((kg ^ ((r >> 1) & 3)) * 8));
    }
#pragma unroll
    for (int n = 0; n < 4; ++n) {
      int c = ((wid & 1) * 64) + n * 16 + lr;
      bfr[n] = *(const bf16x8*)(Bs + c * 32 + ((kg ^ ((c >> 1) & 3)) * 8));
    }
#pragma unroll
    for (int m = 0; m < 4; ++m)
#pragma unroll
      for (int n = 0; n < 4; ++n)
        acc[m][n] = __builtin_amdgcn_mfma_f32_16x16x32_bf16(af[m], bfr[n], acc[m][n], 0, 0, 0);
    buf ^= 1;
  }

  // Epilogue. C/D layout: col = lane&15, row = (lane>>4)*4 + j  [m89-verified]
  const int wr0 = row0 + (wid >> 1) * 64;
  const int wc0 = col0 + (wid & 1) * 64;
  const int rj  = lane >> 4;
  const int cl  = lane & 15;
  if constexpr (STORE == 3) {
    // scores: E[r][c] = bf16(exp2(acc * log2e/32)); rowsum += sum of rounded E
    unsigned short* E = (unsigned short*)Cv + (size_t)bz * 4194304;
    float* rs = aux + bz * 2048;
    const float SC = 0.045084220027780106f;  // log2(e)/32
#pragma unroll
    for (int m = 0; m < 4; ++m) {
#pragma unroll
      for (int j = 0; j < 4; ++j) {
        int r = wr0 + m * 16 + rj * 4 + j;
        float part = 0.f;
#pragma unroll
        for (int n = 0; n < 4; ++n) {
          int c = wc0 + n * 16 + cl;
          unsigned short eb = f2bf(exp2f(acc[m][n][j] * SC));
          E[(size_t)r * 2048 + c] = eb;
          part += __uint_as_float((unsigned)eb << 16);  // sum the rounded values
        }
#pragma unroll
        for (int o = 1; o < 16; o <<= 1) part += __shfl_xor(part, o);
        if (cl == 0) atomicAdd(&rs[r], part);
      }
    }
  } else if constexpr (STORE == 4) {
    // PV: scale by 1/rowsum computed inline (aux holds raw sums)
    float* C = (float*)Cv + (size_t)bz * strideC;
    const float* rs = aux + bz * 2048;
#pragma unroll
    for (int m = 0; m < 4; ++m) {
#pragma unroll
      for (int j = 0; j < 4; ++j) {
        int r = wr0 + m * 16 + rj * 4 + j;
        float inv = 1.0f / rs[r];
#pragma unroll
        for (int n = 0; n < 4; ++n) {
          int c = wc0 + n * 16 + cl;
          C[(size_t)r * ldc + c] = acc[m][n][j] * inv;
        }
      }
    }
  } else {
#pragma unroll
    for (int m = 0; m < 4; ++m) {
#pragma unroll
      for (int n = 0; n < 4; ++n) {
#pragma unroll
        for (int j = 0; j < 4; ++j) {
          int r = wr0 + m * 16 + rj * 4 + j;
          int c = wc0 + n * 16 + cl;
          unsigned short bv = f2bf(acc[m][n][j]);
          if constexpr (STORE == 0) {
            unsigned short* C = (unsigned short*)Cv + (size_t)bz * strideC;
            C[(size_t)r * ldc + c] = bv;
          } else {  // STORE == 2: V transposed per batch [b][o][s]
            unsigned short* C = (unsigned short*)Cv;
            size_t idx = ((size_t)(r >> 11) * 1024 + c) * 2048 + (size_t)(r & 2047);
            C[idx] = bv;
          }
        }
      }
    }
  }
}

extern "C" void kernel_launch(void* const* d_in, const int* in_sizes, int n_in,
                              void* d_out, int out_size, void* d_ws, size_t ws_size,
                              hipStream_t stream) {
  const float* x  = (const float*)d_in[0];
  const float* Wq = (const float*)d_in[1];
  const float* Wk = (const float*)d_in[2];
  const float* Wv = (const float*)d_in[3];

  char* w = (char*)d_ws;
  // ws: xb 16M | W3 6M @16M | Q,K 32M @22M | Vt 16M @54M | E 32M @70M | rs @102M
  unsigned short* xb = (unsigned short*)(w);
  unsigned short* W3 = (unsigned short*)(w + (16ull << 20));  // Wq|Wk|Wv stacked
  unsigned short* QK = (unsigned short*)(w + (22ull << 20));  // Q then K, 8M elems each
  unsigned short* Vt = (unsigned short*)(w + (54ull << 20));  // [b][o][s]
  unsigned short* E  = (unsigned short*)(w + (70ull << 20));  // [b][q][k] bf16 exp
  float*          rs = (float*)        (w + (102ull << 20));  // [b][q] raw rowsum

  hipMemsetAsync(rs, 0, 8192 * sizeof(float), stream);

  // fp32 -> bf16 (x and stacked W3) in one launch
  cvt_all<<<11264, 256, 0, stream>>>(x, Wq, Wk, Wv, xb, W3);

  // Q = x@Wq^T, K = x@Wk^T (z picks weight row-block and output buffer)
  gemm_nt<0><<<dim3(64, 8, 2), 256, 0, stream>>>(
      xb, W3, QK, nullptr, 1024, 1024, 1024, 1024, 0, 1ll << 20, 8ll << 20);
  // V^T = (x@Wv^T)^T, stored [b][o][s]
  gemm_nt<2><<<dim3(64, 8, 1), 256, 0, stream>>>(
      xb, W3 + (2u << 20), Vt, nullptr, 1024, 1024, 0, 1024, 0, 0, 0);
  // E = exp2((Q@K^T)*log2e/32) per batch, bf16; rowsums accumulated atomically
  gemm_nt<3><<<dim3(16, 16, 4), 256, 0, stream>>>(
      QK, QK + (8u << 20), E, rs, 1024, 1024, 2048, 1024,
      2ll << 20, 2ll << 20, 0);
  // out = (E @ V^T) * (1/rowsum), f32 straight to d_out
  gemm_nt<4><<<dim3(16, 8, 4), 256, 0, stream>>>(
      E, Vt, d_out, rs, 2048, 2048, 1024, 2048,
      4ll << 20, 2ll << 20, 2ll << 20);
}